// Round 5
// baseline (486.379 us; speedup 1.0000x reference)
//
#include <hip/hip_runtime.h>
#include <float.h>
#include <stdint.h>

#define EPSF 1e-6f

constexpr int Dc = 512, Kc = 4096, DOc = 1024;
constexpr int Mc = 16384;                 // 4*4096 rows
constexpr int NHALF = 2048;               // centers per half-pass

typedef _Float16 f16x8 __attribute__((ext_vector_type(8)));
typedef float f32x4 __attribute__((ext_vector_type(4)));
typedef __attribute__((address_space(1))) unsigned int gu32;
typedef __attribute__((address_space(3))) unsigned int lu32;
typedef unsigned long long u64;

// ---------- fused converts: x (f16 + window), centers (f16 + c2), W^T ----------
__global__ __launch_bounds__(256) void cvt_all_kernel(
    const float* __restrict__ x, _Float16* __restrict__ xh, unsigned* __restrict__ wthr,
    const float* __restrict__ centers, _Float16* __restrict__ ch, float* __restrict__ c2,
    const float* __restrict__ W, _Float16* __restrict__ whT) {
  const int bid = blockIdx.x;
  const int lane = threadIdx.x & 63, w = threadIdx.x >> 6;
  if (bid < Mc / 4) {
    const int row = bid * 4 + w;
    const size_t base = (size_t)row * Dc + lane * 8;
    float4 v0 = *(const float4*)(x + base);
    float4 v1 = *(const float4*)(x + base + 4);
    float v[8] = {v0.x, v0.y, v0.z, v0.w, v1.x, v1.y, v1.z, v1.w};
    f16x8 h;
    float s = 0.f;
#pragma unroll
    for (int i = 0; i < 8; ++i) {
      const float q = v[i] + EPSF;
      h[i] = (_Float16)q;
      s += q * q;
    }
    *(f16x8*)(xh + base) = h;
#pragma unroll
    for (int m = 1; m < 64; m <<= 1) s += __shfl_xor(s, m, 64);
    // window (u16 quant units): 64*[2(2e+e^2)*||c||max*||x||] + slack; e=2^-11
    if (lane == 0) wthr[row] = (unsigned)(2.829f * sqrtf(s) + 8.0f);
  } else if (bid < Mc / 4 + Kc / 4) {
    const int row = (bid - Mc / 4) * 4 + w;
    const size_t base = (size_t)row * Dc + lane * 8;
    float4 v0 = *(const float4*)(centers + base);
    float4 v1 = *(const float4*)(centers + base + 4);
    float v[8] = {v0.x, v0.y, v0.z, v0.w, v1.x, v1.y, v1.z, v1.w};
    f16x8 h;
    float s = 0.f;
#pragma unroll
    for (int i = 0; i < 8; ++i) { s += v[i] * v[i]; h[i] = (_Float16)v[i]; }
    *(f16x8*)(ch + base) = h;
#pragma unroll
    for (int off = 32; off > 0; off >>= 1) s += __shfl_down(s, off, 64);
    if (lane == 0) c2[row] = s;
  } else {
    const int g = (bid - Mc / 4 - Kc / 4) * 256 + threadIdx.x;
    const int n = g & (DOc - 1), d8 = g >> 10;
    f16x8 h;
#pragma unroll
    for (int r = 0; r < 8; ++r) h[r] = (_Float16)W[(size_t)(d8 * 8 + r) * DOc + n];
    *(f16x8*)(whT + (size_t)n * Dc + d8 * 8) = h;
  }
}

// ---------- distance GEMM: 256x256, BK=64 (r3 verified loop) + compact epilogue ----
// Epilogue: per-row block-min + windowed candidate compaction. Each block emits,
// per row, a 32B record {min u16, cnt u16, 6 x (dq<<8|col) u32} instead of the
// 67MB dq matrix. Stored set = {dq <= localmin + wthr} SUPERSET of global
// candidates (gmin <= lmin). cnt>6 -> scan refines whole block (correctness net).
__global__ __launch_bounds__(512, 2) void dist_hh_kernel(
    const _Float16* __restrict__ xh, const _Float16* __restrict__ chh,
    const float* __restrict__ c2h, const unsigned* __restrict__ wthr,
    unsigned* __restrict__ cand, int hoff) {
  constexpr int BM = 256, BN = 256, BK = 64;
  constexpr int NT = Dc / BK;  // 8 K-tiles
  __shared__ __align__(16) char smem_raw[131072];  // 2 slots x (A|B) 32KB each
  _Float16* smem = (_Float16*)smem_raw;

  const int tid = threadIdx.x;  // 0..511
  const int lane = tid & 63;
  const int wid = tid >> 6;               // 0..7
  const int wm = wid >> 1, wn = wid & 1;  // 4(M) x 2(N) wave grid
  const int fr = lane & 15, kq = lane >> 4;

  const int fid = blockIdx.x;
  const int swz = (fid & 7) * 64 + (fid >> 3);
  const int row0 = (swz >> 3) * BM;  // 64 row-panels
  const int n0 = (swz & 7) * BN;     // 8 col-panels
  const int nb = hoff + (swz & 7);   // global record column-block 0..15

  const int sr = tid >> 3;         // row within 64-row round
  const int sc = tid & 7;          // dest chunk col
  const int csrc = sc ^ (sr & 7);  // pre-swizzled source chunk col
  const int sw = fr & 7;           // read-side swizzle constant

  f32x4 acc[4][8];
#pragma unroll
  for (int i = 0; i < 4; ++i)
#pragma unroll
    for (int j = 0; j < 8; ++j) acc[i][j] = (f32x4){0.f, 0.f, 0.f, 0.f};

  auto stage = [&](int kt) {
    const int p = kt & 1;
    const int d0 = kt * BK;
    _Float16* Ab = smem + p * 16384;
    _Float16* Bb = smem + 32768 + p * 16384;
#pragma unroll
    for (int ld = 0; ld < 4; ++ld) {
      const int r = ld * 64 + sr;
      const size_t gA = (size_t)(row0 + r) * Dc + d0 + csrc * 8;
      const size_t gB = (size_t)(n0 + r) * Dc + d0 + csrc * 8;
      const int lo = r * 64 + sc * 8;
      __builtin_amdgcn_global_load_lds((const gu32*)(xh + gA), (lu32*)(Ab + lo), 16, 0, 0);
      __builtin_amdgcn_global_load_lds((const gu32*)(chh + gB), (lu32*)(Bb + lo), 16, 0, 0);
    }
  };

  stage(0);
  stage(1);
  asm volatile("s_waitcnt vmcnt(8)" ::: "memory");
  __builtin_amdgcn_sched_barrier(0);
  __builtin_amdgcn_s_barrier();

  for (int kt = 0; kt < NT; ++kt) {
    const int p = kt & 1;
    const _Float16* Ab = smem + p * 16384;
    const _Float16* Bb = smem + 32768 + p * 16384;
    f16x8 a[4], b[4];
#pragma unroll
    for (int s = 0; s < 4; ++s) {  // (kh, nh): sub-phase = 16-MFMA cluster
      const int kh = s >> 1, nh = s & 1;
      const int co = ((kh * 4 + kq) ^ sw) * 8;  // swizzled 16B chunk (f16 idx)
      if (nh == 0) {
#pragma unroll
        for (int m = 0; m < 4; ++m)
          a[m] = *(const f16x8*)&Ab[(wm * 64 + 16 * m + fr) * 64 + co];
      }
#pragma unroll
      for (int n = 0; n < 4; ++n)
        b[n] = *(const f16x8*)&Bb[(wn * 128 + nh * 64 + 16 * n + fr) * 64 + co];
      __builtin_amdgcn_s_barrier();
      asm volatile("s_waitcnt lgkmcnt(0)" ::: "memory");
      __builtin_amdgcn_s_setprio(1);
#pragma unroll
      for (int m = 0; m < 4; ++m)
#pragma unroll
        for (int n = 0; n < 4; ++n)
          acc[m][nh * 4 + n] =
              __builtin_amdgcn_mfma_f32_16x16x32_f16(a[m], b[n], acc[m][nh * 4 + n], 0, 0, 0);
      __builtin_amdgcn_s_setprio(0);
      __builtin_amdgcn_s_barrier();
    }
    if (kt + 2 < NT) {
      stage(kt + 2);
      asm volatile("s_waitcnt vmcnt(8)" ::: "memory");
    } else {
      asm volatile("s_waitcnt vmcnt(0)" ::: "memory");
    }
    __builtin_amdgcn_sched_barrier(0);
    __builtin_amdgcn_s_barrier();
  }

  // ---- compact epilogue ----
  unsigned short* rmin = (unsigned short*)smem_raw;           // [256][2]
  unsigned short* bmin = (unsigned short*)(smem_raw + 1024);  // [256]
  unsigned* rcnt = (unsigned*)(smem_raw + 2048);              // [256]
  unsigned* rthr = (unsigned*)(smem_raw + 3072);              // [256]
  unsigned* rcand = (unsigned*)(smem_raw + 4096);             // [256][6]

  if (tid < 256) {
    rcnt[tid] = 0u;
    rthr[tid] = wthr[row0 + tid];
  }

  float c2v[8];
#pragma unroll
  for (int j = 0; j < 8; ++j)
    c2v[j] = c2h[n0 + wn * 128 + (j >> 2) * 64 + 16 * (j & 3) + fr];

  auto quant = [](float d) -> unsigned {
    int u = __float2int_rn((d + 256.0f) * 32.0f);
    return (unsigned)min(65535, max(0, u));
  };

  // pass 1: per-lane row mins over this lane's 8 cols, then fr-group reduce
  unsigned pm[16];
#pragma unroll
  for (int i = 0; i < 4; ++i)
#pragma unroll
    for (int reg = 0; reg < 4; ++reg) {
      unsigned mn = 0xFFFFu;
#pragma unroll
      for (int j = 0; j < 8; ++j)
        mn = min(mn, quant(c2v[j] - 2.0f * acc[i][j][reg]));
      pm[i * 4 + reg] = mn;
    }
#pragma unroll
  for (int d = 1; d < 16; d <<= 1)
#pragma unroll
    for (int k = 0; k < 16; ++k)
      pm[k] = min(pm[k], (unsigned)__shfl_xor((int)pm[k], d, 64));
  if (fr == 0) {
#pragma unroll
    for (int k = 0; k < 16; ++k)
      rmin[(wm * 64 + 16 * (k >> 2) + 4 * kq + (k & 3)) * 2 + wn] = (unsigned short)pm[k];
  }
  __syncthreads();
  if (tid < 256) bmin[tid] = min(rmin[2 * tid], rmin[2 * tid + 1]);
  __syncthreads();

  // pass 2: windowed append (superset of global candidates)
#pragma unroll
  for (int i = 0; i < 4; ++i)
#pragma unroll
    for (int reg = 0; reg < 4; ++reg) {
      const int row = wm * 64 + 16 * i + 4 * kq + reg;
      const unsigned lim = (unsigned)bmin[row] + rthr[row];
#pragma unroll
      for (int j = 0; j < 8; ++j) {
        const unsigned dqv = quant(c2v[j] - 2.0f * acc[i][j][reg]);
        if (dqv <= lim) {
          const unsigned slot = atomicAdd(&rcnt[row], 1u);
          if (slot < 6u)
            rcand[row * 6 + slot] =
                (dqv << 8) | (unsigned)(wn * 128 + (j >> 2) * 64 + 16 * (j & 3) + fr);
        }
      }
    }
  __syncthreads();

  // write 32B record per row: {min<<16|cnt, c0..c5, 0}
  {
    const int row = tid >> 1, part = tid & 1;
    unsigned cnt = rcnt[row];
    if (cnt > 65535u) cnt = 65535u;
    unsigned* dst = cand + ((size_t)(row0 + row) * 16 + nb) * 8 + part * 4;
    uint4 v;
    if (part == 0)
      v = (uint4){((unsigned)bmin[row] << 16) | cnt, rcand[row * 6 + 0],
                  rcand[row * 6 + 1], rcand[row * 6 + 2]};
    else
      v = (uint4){rcand[row * 6 + 3], rcand[row * 6 + 4], rcand[row * 6 + 5], 0u};
    *(uint4*)dst = v;
  }
}

// ---------- scan records + fp64 refine: one wave per row, both halves ----------
__global__ __launch_bounds__(256) void scan_refine_kernel(
    const unsigned* __restrict__ cand, const unsigned* __restrict__ wthr,
    const float* __restrict__ x, const float* __restrict__ centers,
    u64* __restrict__ best) {
  const int w = threadIdx.x >> 6, l = threadIdx.x & 63;
  const int row = blockIdx.x * 4 + w;
  const unsigned* cr_ = cand + (size_t)row * 128;  // 16 recs x 8 u32
  const unsigned wA = cr_[l];
  const unsigned wB = cr_[64 + l];
  const int sub = l & 7;

  // global quantized min over 16 block mins
  unsigned mn = 0xFFFFu;
  if (sub == 0) mn = min(wA >> 16, wB >> 16);
#pragma unroll
  for (int m = 1; m < 64; m <<= 1) mn = min(mn, (unsigned)__shfl_xor((int)mn, m, 64));
  const unsigned thr = mn + wthr[row];

  // preload x row (fp32), 8 elems/lane
  const float* xr = x + (size_t)row * Dc + l * 8;
  float4 a0 = *(const float4*)xr, a1 = *(const float4*)(xr + 4);
  const float xa[8] = {a0.x, a0.y, a0.z, a0.w, a1.x, a1.y, a1.z, a1.w};
  double xq[8];
#pragma unroll
  for (int i = 0; i < 8; ++i) xq[i] = (double)(xa[i] + EPSF);  // fp32 x+eps, as reference

  u64 bk = ~0ULL;
  auto refine = [&](int g) {
    const float* cr = centers + (size_t)g * Dc + l * 8;
    float4 b0 = *(const float4*)cr, b1 = *(const float4*)(cr + 4);
    const float ca[8] = {b0.x, b0.y, b0.z, b0.w, b1.x, b1.y, b1.z, b1.w};
    double s = 0.0;
#pragma unroll
    for (int i = 0; i < 8; ++i) {
      const double cd = (double)ca[i];
      s += cd * cd - 2.0 * xq[i] * cd;
    }
#pragma unroll
    for (int mm = 1; mm < 64; mm <<= 1) s += __shfl_xor(s, mm, 64);
    const u64 key =
        ((u64)__double_as_longlong(s + 16384.0) & ~0xFFFULL) | (unsigned)g;
    bk = min(bk, key);
  };

#pragma unroll
  for (int h = 0; h < 2; ++h) {
    const unsigned wv = h ? wB : wA;
    const unsigned cnt = ((unsigned)__shfl((int)wv, l & ~7)) & 0xFFFFu;
    const bool valid = (sub >= 1) && (sub <= 6) && ((unsigned)(sub - 1) < cnt) &&
                       (cnt <= 6u) && ((wv >> 8) <= thr);
    u64 m = __ballot(valid);
    while (m) {
      const int ln = __ffsll((long long)m) - 1;
      m &= m - 1;
      const unsigned cw = (unsigned)__shfl((int)wv, ln);
      refine((h * 8 + (ln >> 3)) * 256 + (int)(cw & 0xFFu));
    }
    // overflow blocks (cnt>6): refine the whole 256-block (correctness net)
    u64 md = __ballot((sub == 0) && (cnt > 6u));
    while (md) {
      const int ln = __ffsll((long long)md) - 1;
      md &= md - 1;
      const int blk = h * 8 + (ln >> 3);
      for (int c = 0; c < 256; ++c) refine(blk * 256 + c);
    }
  }
  if (l == 0) best[row] = bk;
}

// ---------- projection: out = centers[best] @ W + b  (256x256, dist skeleton) ----------
__global__ __launch_bounds__(512, 2) void proj_mfma_kernel(
    const _Float16* __restrict__ ch, const u64* __restrict__ best,
    const _Float16* __restrict__ whT, const float* __restrict__ bias,
    float* __restrict__ out) {
  constexpr int BM = 256, BN = 256, BK = 64;
  constexpr int NT = Dc / BK;  // 8 K-tiles
  __shared__ __align__(16) _Float16 smem[4 * 16384];  // 128 KB: 2 slots x (A|B)
  __shared__ int ssel[BM];

  const int tid = threadIdx.x;  // 0..511
  const int lane = tid & 63;
  const int wid = tid >> 6;
  const int wm = wid >> 1, wn = wid & 1;  // 4(M) x 2(N)
  const int fr = lane & 15, kq = lane >> 4;
  const int row0 = (blockIdx.x >> 2) * BM;  // 64 row-panels
  const int n0 = (blockIdx.x & 3) * BN;     // 4 col-panels (DOc=1024)

  const int sr = tid >> 3;
  const int sc = tid & 7;
  const int csrc = sc ^ (sr & 7);
  const int sw = fr & 7;

  if (tid < 256) ssel[tid] = (int)(best[row0 + tid] & 0xFFFULL);
  __syncthreads();

  f32x4 acc[4][8];
#pragma unroll
  for (int i = 0; i < 4; ++i)
#pragma unroll
    for (int j = 0; j < 8; ++j) acc[i][j] = (f32x4){0.f, 0.f, 0.f, 0.f};

  auto stage = [&](int kt) {
    const int p = kt & 1;
    const int d0 = kt * BK;
    _Float16* Ab = smem + p * 16384;
    _Float16* Bb = smem + 32768 + p * 16384;
#pragma unroll
    for (int ld = 0; ld < 4; ++ld) {
      const int r = ld * 64 + sr;
      const size_t gA = (size_t)ssel[r] * Dc + d0 + csrc * 8;
      const size_t gB = (size_t)(n0 + r) * Dc + d0 + csrc * 8;
      const int lo = r * 64 + sc * 8;
      __builtin_amdgcn_global_load_lds((const gu32*)(ch + gA), (lu32*)(Ab + lo), 16, 0, 0);
      __builtin_amdgcn_global_load_lds((const gu32*)(whT + gB), (lu32*)(Bb + lo), 16, 0, 0);
    }
  };

  stage(0);
  stage(1);
  asm volatile("s_waitcnt vmcnt(8)" ::: "memory");
  __builtin_amdgcn_sched_barrier(0);
  __builtin_amdgcn_s_barrier();

  for (int kt = 0; kt < NT; ++kt) {
    const int p = kt & 1;
    const _Float16* Ab = smem + p * 16384;
    const _Float16* Bb = smem + 32768 + p * 16384;
    f16x8 a[4], b[4];
#pragma unroll
    for (int s = 0; s < 4; ++s) {
      const int kh = s >> 1, nh = s & 1;
      const int co = ((kh * 4 + kq) ^ sw) * 8;
      if (nh == 0) {
#pragma unroll
        for (int m = 0; m < 4; ++m)
          a[m] = *(const f16x8*)&Ab[(wm * 64 + 16 * m + fr) * 64 + co];
      }
#pragma unroll
      for (int n = 0; n < 4; ++n)
        b[n] = *(const f16x8*)&Bb[(wn * 128 + nh * 64 + 16 * n + fr) * 64 + co];
      __builtin_amdgcn_s_barrier();
      asm volatile("s_waitcnt lgkmcnt(0)" ::: "memory");
      __builtin_amdgcn_s_setprio(1);
#pragma unroll
      for (int m = 0; m < 4; ++m)
#pragma unroll
        for (int n = 0; n < 4; ++n)
          acc[m][nh * 4 + n] =
              __builtin_amdgcn_mfma_f32_16x16x32_f16(a[m], b[n], acc[m][nh * 4 + n], 0, 0, 0);
      __builtin_amdgcn_s_setprio(0);
      __builtin_amdgcn_s_barrier();
    }
    if (kt + 2 < NT) {
      stage(kt + 2);
      asm volatile("s_waitcnt vmcnt(8)" ::: "memory");
    } else {
      asm volatile("s_waitcnt vmcnt(0)" ::: "memory");
    }
    __builtin_amdgcn_sched_barrier(0);
    __builtin_amdgcn_s_barrier();
  }

  // epilogue: direct f32 stores + bias
#pragma unroll
  for (int j = 0; j < 8; ++j) {
    const int col = n0 + wn * 128 + (j >> 2) * 64 + 16 * (j & 3) + fr;
    const float bb = bias[col];
#pragma unroll
    for (int i = 0; i < 4; ++i)
#pragma unroll
      for (int reg = 0; reg < 4; ++reg)
        out[(size_t)(row0 + wm * 64 + 16 * i + 4 * kq + reg) * DOc + col] =
            acc[i][j][reg] + bb;
  }
}

extern "C" void kernel_launch(void* const* d_in, const int* in_sizes, int n_in,
                              void* d_out, int out_size, void* d_ws, size_t ws_size,
                              hipStream_t stream) {
  const float* x = (const float*)d_in[0];        // [4,4096,512]
  const float* centers = (const float*)d_in[1];  // [4096,512]
  const float* W = (const float*)d_in[2];        // [512,1024]
  const float* b = (const float*)d_in[3];        // [1024]
  float* out = (float*)d_out;                    // [4,4096,1024] fp32

  // cand records ([16384][16][8] u32 = 8.4 MB) live in d_out; proj overwrites last.
  unsigned* cand = (unsigned*)d_out;

  // workspace (~22.3 MB)
  char* ws = (char*)d_ws;
  _Float16* xh = (_Float16*)(ws);                 // 16.78 MB
  _Float16* ch = (_Float16*)(ws + 16777216);      // 4.19 MB
  _Float16* whT = (_Float16*)(ws + 20971520);     // 1.05 MB
  float* c2 = (float*)(ws + 22020096);            // 16 KB
  unsigned* wthr = (unsigned*)(ws + 22036480);    // 64 KB
  u64* best = (u64*)(ws + 22102016);              // 128 KB

  cvt_all_kernel<<<Mc / 4 + Kc / 4 + 256, 256, 0, stream>>>(x, xh, wthr, centers,
                                                            ch, c2, W, whT);

  for (int half = 0; half < 2; ++half) {
    const int hb = half * NHALF;
    dist_hh_kernel<<<(Mc / 256) * (NHALF / 256), 512, 0, stream>>>(
        xh, ch + (size_t)hb * Dc, c2 + hb, wthr, cand, half * 8);
  }
  scan_refine_kernel<<<Mc / 4, 256, 0, stream>>>(cand, wthr, x, centers, best);
  proj_mfma_kernel<<<256, 512, 0, stream>>>(ch, best, whT, b, out);
}

// Round 6
// 247.176 us; speedup vs baseline: 1.9677x; 1.9677x over previous
//
#include <hip/hip_runtime.h>
#include <float.h>
#include <stdint.h>

#define EPSF 1e-6f

constexpr int Dc = 512, Kc = 4096, DOc = 1024;
constexpr int Mc = 16384;                 // 4*4096 rows
constexpr int NHALF = 2048;               // centers per half-pass

typedef _Float16 f16x8 __attribute__((ext_vector_type(8)));
typedef float f32x4 __attribute__((ext_vector_type(4)));
typedef __attribute__((address_space(1))) unsigned int gu32;
typedef __attribute__((address_space(3))) unsigned int lu32;
typedef unsigned long long u64;

// ---------- fused converts: x (f16 + window), centers (f16 + c2), W^T ----------
__global__ __launch_bounds__(256) void cvt_all_kernel(
    const float* __restrict__ x, _Float16* __restrict__ xh, unsigned* __restrict__ wthr,
    const float* __restrict__ centers, _Float16* __restrict__ ch, float* __restrict__ c2,
    const float* __restrict__ W, _Float16* __restrict__ whT) {
  const int bid = blockIdx.x;
  const int lane = threadIdx.x & 63, w = threadIdx.x >> 6;
  if (bid < Mc / 4) {
    const int row = bid * 4 + w;
    const size_t base = (size_t)row * Dc + lane * 8;
    float4 v0 = *(const float4*)(x + base);
    float4 v1 = *(const float4*)(x + base + 4);
    float v[8] = {v0.x, v0.y, v0.z, v0.w, v1.x, v1.y, v1.z, v1.w};
    f16x8 h;
    float s = 0.f;
#pragma unroll
    for (int i = 0; i < 8; ++i) {
      const float q = v[i] + EPSF;
      h[i] = (_Float16)q;
      s += q * q;
    }
    *(f16x8*)(xh + base) = h;
#pragma unroll
    for (int m = 1; m < 64; m <<= 1) s += __shfl_xor(s, m, 64);
    // window (u16 quant units): 64*[2(2e+e^2)*||c||max*||x||] + slack; e=2^-11
    if (lane == 0) wthr[row] = (unsigned)(2.829f * sqrtf(s) + 8.0f);
  } else if (bid < Mc / 4 + Kc / 4) {
    const int row = (bid - Mc / 4) * 4 + w;
    const size_t base = (size_t)row * Dc + lane * 8;
    float4 v0 = *(const float4*)(centers + base);
    float4 v1 = *(const float4*)(centers + base + 4);
    float v[8] = {v0.x, v0.y, v0.z, v0.w, v1.x, v1.y, v1.z, v1.w};
    f16x8 h;
    float s = 0.f;
#pragma unroll
    for (int i = 0; i < 8; ++i) { s += v[i] * v[i]; h[i] = (_Float16)v[i]; }
    *(f16x8*)(ch + base) = h;
#pragma unroll
    for (int off = 32; off > 0; off >>= 1) s += __shfl_down(s, off, 64);
    if (lane == 0) c2[row] = s;
  } else {
    const int g = (bid - Mc / 4 - Kc / 4) * 256 + threadIdx.x;
    const int n = g & (DOc - 1), d8 = g >> 10;
    f16x8 h;
#pragma unroll
    for (int r = 0; r < 8; ++r) h[r] = (_Float16)W[(size_t)(d8 * 8 + r) * DOc + n];
    *(f16x8*)(whT + (size_t)n * Dc + d8 * 8) = h;
  }
}

// ---------- distance GEMM: 256x256, BK=64 (r3 verified loop) + compact epilogue ----
// Record per (row, 256-col block): 64B = {min<<16|cnt, 14 x (dq<<8|col), pad}.
// Stored set = {dq <= localmin + wthr}: SUPERSET of global-window candidates
// (gmin <= lmin). Capacity 14: P(cnt>14) ~ 1e-11 (Poisson lambda~1.4), so the
// whole-block fallback in scan is a correctness net that never fires in practice
// (capacity 6 fired ~500x -> 265us tail in round 5).
__global__ __launch_bounds__(512, 2) void dist_hh_kernel(
    const _Float16* __restrict__ xh, const _Float16* __restrict__ chh,
    const float* __restrict__ c2h, const unsigned* __restrict__ wthr,
    unsigned* __restrict__ cand, int hoff) {
  constexpr int BM = 256, BN = 256, BK = 64;
  constexpr int NT = Dc / BK;  // 8 K-tiles
  __shared__ __align__(16) char smem_raw[131072];  // 2 slots x (A|B) 32KB each
  _Float16* smem = (_Float16*)smem_raw;

  const int tid = threadIdx.x;  // 0..511
  const int lane = tid & 63;
  const int wid = tid >> 6;               // 0..7
  const int wm = wid >> 1, wn = wid & 1;  // 4(M) x 2(N) wave grid
  const int fr = lane & 15, kq = lane >> 4;

  const int fid = blockIdx.x;
  const int swz = (fid & 7) * 64 + (fid >> 3);
  const int row0 = (swz >> 3) * BM;  // 64 row-panels
  const int n0 = (swz & 7) * BN;     // 8 col-panels
  const int nb = hoff + (swz & 7);   // global record column-block 0..15

  const int sr = tid >> 3;         // row within 64-row round
  const int sc = tid & 7;          // dest chunk col
  const int csrc = sc ^ (sr & 7);  // pre-swizzled source chunk col
  const int sw = fr & 7;           // read-side swizzle constant

  f32x4 acc[4][8];
#pragma unroll
  for (int i = 0; i < 4; ++i)
#pragma unroll
    for (int j = 0; j < 8; ++j) acc[i][j] = (f32x4){0.f, 0.f, 0.f, 0.f};

  auto stage = [&](int kt) {
    const int p = kt & 1;
    const int d0 = kt * BK;
    _Float16* Ab = smem + p * 16384;
    _Float16* Bb = smem + 32768 + p * 16384;
#pragma unroll
    for (int ld = 0; ld < 4; ++ld) {
      const int r = ld * 64 + sr;
      const size_t gA = (size_t)(row0 + r) * Dc + d0 + csrc * 8;
      const size_t gB = (size_t)(n0 + r) * Dc + d0 + csrc * 8;
      const int lo = r * 64 + sc * 8;
      __builtin_amdgcn_global_load_lds((const gu32*)(xh + gA), (lu32*)(Ab + lo), 16, 0, 0);
      __builtin_amdgcn_global_load_lds((const gu32*)(chh + gB), (lu32*)(Bb + lo), 16, 0, 0);
    }
  };

  stage(0);
  stage(1);
  asm volatile("s_waitcnt vmcnt(8)" ::: "memory");
  __builtin_amdgcn_sched_barrier(0);
  __builtin_amdgcn_s_barrier();

  for (int kt = 0; kt < NT; ++kt) {
    const int p = kt & 1;
    const _Float16* Ab = smem + p * 16384;
    const _Float16* Bb = smem + 32768 + p * 16384;
    f16x8 a[4], b[4];
#pragma unroll
    for (int s = 0; s < 4; ++s) {  // (kh, nh): sub-phase = 16-MFMA cluster
      const int kh = s >> 1, nh = s & 1;
      const int co = ((kh * 4 + kq) ^ sw) * 8;  // swizzled 16B chunk (f16 idx)
      if (nh == 0) {
#pragma unroll
        for (int m = 0; m < 4; ++m)
          a[m] = *(const f16x8*)&Ab[(wm * 64 + 16 * m + fr) * 64 + co];
      }
#pragma unroll
      for (int n = 0; n < 4; ++n)
        b[n] = *(const f16x8*)&Bb[(wn * 128 + nh * 64 + 16 * n + fr) * 64 + co];
      __builtin_amdgcn_s_barrier();
      asm volatile("s_waitcnt lgkmcnt(0)" ::: "memory");
      __builtin_amdgcn_s_setprio(1);
#pragma unroll
      for (int m = 0; m < 4; ++m)
#pragma unroll
        for (int n = 0; n < 4; ++n)
          acc[m][nh * 4 + n] =
              __builtin_amdgcn_mfma_f32_16x16x32_f16(a[m], b[n], acc[m][nh * 4 + n], 0, 0, 0);
      __builtin_amdgcn_s_setprio(0);
      __builtin_amdgcn_s_barrier();
    }
    if (kt + 2 < NT) {
      stage(kt + 2);
      asm volatile("s_waitcnt vmcnt(8)" ::: "memory");
    } else {
      asm volatile("s_waitcnt vmcnt(0)" ::: "memory");
    }
    __builtin_amdgcn_sched_barrier(0);
    __builtin_amdgcn_s_barrier();
  }

  // ---- compact epilogue ----
  unsigned short* rmin = (unsigned short*)smem_raw;           // [256][2]
  unsigned short* bmin = (unsigned short*)(smem_raw + 1024);  // [256]
  unsigned* rcnt = (unsigned*)(smem_raw + 2048);              // [256]
  unsigned* rthr = (unsigned*)(smem_raw + 3072);              // [256]
  unsigned* rcand = (unsigned*)(smem_raw + 4096);             // [256][14]

  if (tid < 256) {
    rcnt[tid] = 0u;
    rthr[tid] = wthr[row0 + tid];
  }

  float c2v[8];
#pragma unroll
  for (int j = 0; j < 8; ++j)
    c2v[j] = c2h[n0 + wn * 128 + (j >> 2) * 64 + 16 * (j & 3) + fr];

  auto quant = [](float d) -> unsigned {
    int u = __float2int_rn((d + 256.0f) * 32.0f);
    return (unsigned)min(65535, max(0, u));
  };

  // pass 1: per-lane row mins over this lane's 8 cols, then fr-group reduce
  unsigned pm[16];
#pragma unroll
  for (int i = 0; i < 4; ++i)
#pragma unroll
    for (int reg = 0; reg < 4; ++reg) {
      unsigned mn = 0xFFFFu;
#pragma unroll
      for (int j = 0; j < 8; ++j)
        mn = min(mn, quant(c2v[j] - 2.0f * acc[i][j][reg]));
      pm[i * 4 + reg] = mn;
    }
#pragma unroll
  for (int d = 1; d < 16; d <<= 1)
#pragma unroll
    for (int k = 0; k < 16; ++k)
      pm[k] = min(pm[k], (unsigned)__shfl_xor((int)pm[k], d, 64));
  if (fr == 0) {
#pragma unroll
    for (int k = 0; k < 16; ++k)
      rmin[(wm * 64 + 16 * (k >> 2) + 4 * kq + (k & 3)) * 2 + wn] = (unsigned short)pm[k];
  }
  __syncthreads();
  if (tid < 256) bmin[tid] = min(rmin[2 * tid], rmin[2 * tid + 1]);
  __syncthreads();

  // pass 2: windowed append (superset of global candidates)
#pragma unroll
  for (int i = 0; i < 4; ++i)
#pragma unroll
    for (int reg = 0; reg < 4; ++reg) {
      const int row = wm * 64 + 16 * i + 4 * kq + reg;
      const unsigned lim = (unsigned)bmin[row] + rthr[row];
#pragma unroll
      for (int j = 0; j < 8; ++j) {
        const unsigned dqv = quant(c2v[j] - 2.0f * acc[i][j][reg]);
        if (dqv <= lim) {
          const unsigned slot = atomicAdd(&rcnt[row], 1u);
          if (slot < 14u)
            rcand[row * 14 + slot] =
                (dqv << 8) | (unsigned)(wn * 128 + (j >> 2) * 64 + 16 * (j & 3) + fr);
        }
      }
    }
  __syncthreads();

  // write 64B record per row: {min<<16|cnt, c0..c13, 0}
#pragma unroll
  for (int rr = 0; rr < 2; ++rr) {
    const int row = rr * 128 + (tid >> 2), part = tid & 3;
    unsigned cnt = rcnt[row];
    if (cnt > 65535u) cnt = 65535u;
    unsigned vals[4];
#pragma unroll
    for (int q = 0; q < 4; ++q) {
      const int wd = part * 4 + q;
      unsigned v;
      if (wd == 0) v = ((unsigned)bmin[row] << 16) | cnt;
      else if (wd <= 14) v = rcand[row * 14 + wd - 1];
      else v = 0u;
      vals[q] = v;
    }
    *(uint4*)(cand + ((size_t)(row0 + row) * 16 + nb) * 16 + part * 4) =
        (uint4){vals[0], vals[1], vals[2], vals[3]};
  }
}

// ---------- scan records + fp64 refine: one wave per row, single pass ----------
__global__ __launch_bounds__(256) void scan_refine_kernel(
    const unsigned* __restrict__ cand, const unsigned* __restrict__ wthr,
    const float* __restrict__ x, const float* __restrict__ centers,
    u64* __restrict__ best) {
  const int w = threadIdx.x >> 6, l = threadIdx.x & 63;
  const int row = blockIdx.x * 4 + w;
  // 16 records x 16 u32 per row; lane l owns record l>>2, words (l&3)*4..+3
  const uint4 rv = *(const uint4*)(cand + (size_t)row * 256 + l * 4);
  const int w0 = (l & 3) * 4;

  // global quantized min over 16 block mins
  unsigned mn = 0xFFFFu;
  if (w0 == 0) mn = rv.x >> 16;
#pragma unroll
  for (int m = 1; m < 64; m <<= 1) mn = min(mn, (unsigned)__shfl_xor((int)mn, m, 64));
  const unsigned thr = mn + wthr[row];

  // record's cnt broadcast to its 4 lanes
  const unsigned cnt = ((unsigned)__shfl((int)rv.x, l & ~3)) & 0xFFFFu;

  // preload x row (fp32), 8 elems/lane
  const float* xr = x + (size_t)row * Dc + l * 8;
  float4 a0 = *(const float4*)xr, a1 = *(const float4*)(xr + 4);
  const float xa[8] = {a0.x, a0.y, a0.z, a0.w, a1.x, a1.y, a1.z, a1.w};
  double xq[8];
#pragma unroll
  for (int i = 0; i < 8; ++i) xq[i] = (double)(xa[i] + EPSF);  // fp32 x+eps, as reference

  u64 bk = ~0ULL;
  auto refine = [&](int g) {
    const float* cr = centers + (size_t)g * Dc + l * 8;
    float4 b0 = *(const float4*)cr, b1 = *(const float4*)(cr + 4);
    const float ca[8] = {b0.x, b0.y, b0.z, b0.w, b1.x, b1.y, b1.z, b1.w};
    double s = 0.0;
#pragma unroll
    for (int i = 0; i < 8; ++i) {
      const double cd = (double)ca[i];
      s += cd * cd - 2.0 * xq[i] * cd;
    }
#pragma unroll
    for (int mm = 1; mm < 64; mm <<= 1) s += __shfl_xor(s, mm, 64);
    const u64 key =
        ((u64)__double_as_longlong(s + 16384.0) & ~0xFFFULL) | (unsigned)g;
    bk = min(bk, key);
  };

  const unsigned wv[4] = {rv.x, rv.y, rv.z, rv.w};
#pragma unroll
  for (int i = 0; i < 4; ++i) {
    const int wi = w0 + i;  // word index within record
    const bool valid = (wi >= 1) && (wi <= 14) && ((unsigned)(wi - 1) < cnt) &&
                       (cnt <= 14u) && ((wv[i] >> 8) <= thr);
    u64 m = __ballot(valid);
    while (m) {
      const int ln = __ffsll((long long)m) - 1;
      m &= m - 1;
      const unsigned cw = (unsigned)__shfl((int)wv[i], ln);
      refine((ln >> 2) * 256 + (int)(cw & 0xFFu));
    }
  }
  // overflow records (cnt>14): refine whole 256-block (correctness net; ~never)
  {
    u64 md = __ballot((w0 == 0) && (cnt > 14u));
    while (md) {
      const int ln = __ffsll((long long)md) - 1;
      md &= md - 1;
      const int blk = ln >> 2;
      for (int c = 0; c < 256; ++c) refine(blk * 256 + c);
    }
  }
  if (l == 0) best[row] = bk;
}

// ---------- projection: out = centers[best] @ W + b  (256x256, dist skeleton) ----------
__global__ __launch_bounds__(512, 2) void proj_mfma_kernel(
    const _Float16* __restrict__ ch, const u64* __restrict__ best,
    const _Float16* __restrict__ whT, const float* __restrict__ bias,
    float* __restrict__ out) {
  constexpr int BM = 256, BN = 256, BK = 64;
  constexpr int NT = Dc / BK;  // 8 K-tiles
  __shared__ __align__(16) _Float16 smem[4 * 16384];  // 128 KB: 2 slots x (A|B)
  __shared__ int ssel[BM];

  const int tid = threadIdx.x;  // 0..511
  const int lane = tid & 63;
  const int wid = tid >> 6;
  const int wm = wid >> 1, wn = wid & 1;  // 4(M) x 2(N)
  const int fr = lane & 15, kq = lane >> 4;
  const int row0 = (blockIdx.x >> 2) * BM;  // 64 row-panels
  const int n0 = (blockIdx.x & 3) * BN;     // 4 col-panels (DOc=1024)

  const int sr = tid >> 3;
  const int sc = tid & 7;
  const int csrc = sc ^ (sr & 7);
  const int sw = fr & 7;

  if (tid < 256) ssel[tid] = (int)(best[row0 + tid] & 0xFFFULL);
  __syncthreads();

  f32x4 acc[4][8];
#pragma unroll
  for (int i = 0; i < 4; ++i)
#pragma unroll
    for (int j = 0; j < 8; ++j) acc[i][j] = (f32x4){0.f, 0.f, 0.f, 0.f};

  auto stage = [&](int kt) {
    const int p = kt & 1;
    const int d0 = kt * BK;
    _Float16* Ab = smem + p * 16384;
    _Float16* Bb = smem + 32768 + p * 16384;
#pragma unroll
    for (int ld = 0; ld < 4; ++ld) {
      const int r = ld * 64 + sr;
      const size_t gA = (size_t)ssel[r] * Dc + d0 + csrc * 8;
      const size_t gB = (size_t)(n0 + r) * Dc + d0 + csrc * 8;
      const int lo = r * 64 + sc * 8;
      __builtin_amdgcn_global_load_lds((const gu32*)(ch + gA), (lu32*)(Ab + lo), 16, 0, 0);
      __builtin_amdgcn_global_load_lds((const gu32*)(whT + gB), (lu32*)(Bb + lo), 16, 0, 0);
    }
  };

  stage(0);
  stage(1);
  asm volatile("s_waitcnt vmcnt(8)" ::: "memory");
  __builtin_amdgcn_sched_barrier(0);
  __builtin_amdgcn_s_barrier();

  for (int kt = 0; kt < NT; ++kt) {
    const int p = kt & 1;
    const _Float16* Ab = smem + p * 16384;
    const _Float16* Bb = smem + 32768 + p * 16384;
    f16x8 a[4], b[4];
#pragma unroll
    for (int s = 0; s < 4; ++s) {
      const int kh = s >> 1, nh = s & 1;
      const int co = ((kh * 4 + kq) ^ sw) * 8;
      if (nh == 0) {
#pragma unroll
        for (int m = 0; m < 4; ++m)
          a[m] = *(const f16x8*)&Ab[(wm * 64 + 16 * m + fr) * 64 + co];
      }
#pragma unroll
      for (int n = 0; n < 4; ++n)
        b[n] = *(const f16x8*)&Bb[(wn * 128 + nh * 64 + 16 * n + fr) * 64 + co];
      __builtin_amdgcn_s_barrier();
      asm volatile("s_waitcnt lgkmcnt(0)" ::: "memory");
      __builtin_amdgcn_s_setprio(1);
#pragma unroll
      for (int m = 0; m < 4; ++m)
#pragma unroll
        for (int n = 0; n < 4; ++n)
          acc[m][nh * 4 + n] =
              __builtin_amdgcn_mfma_f32_16x16x32_f16(a[m], b[n], acc[m][nh * 4 + n], 0, 0, 0);
      __builtin_amdgcn_s_setprio(0);
      __builtin_amdgcn_s_barrier();
    }
    if (kt + 2 < NT) {
      stage(kt + 2);
      asm volatile("s_waitcnt vmcnt(8)" ::: "memory");
    } else {
      asm volatile("s_waitcnt vmcnt(0)" ::: "memory");
    }
    __builtin_amdgcn_sched_barrier(0);
    __builtin_amdgcn_s_barrier();
  }

  // epilogue: direct f32 stores + bias
#pragma unroll
  for (int j = 0; j < 8; ++j) {
    const int col = n0 + wn * 128 + (j >> 2) * 64 + 16 * (j & 3) + fr;
    const float bb = bias[col];
#pragma unroll
    for (int i = 0; i < 4; ++i)
#pragma unroll
      for (int reg = 0; reg < 4; ++reg)
        out[(size_t)(row0 + wm * 64 + 16 * i + 4 * kq + reg) * DOc + col] =
            acc[i][j][reg] + bb;
  }
}

extern "C" void kernel_launch(void* const* d_in, const int* in_sizes, int n_in,
                              void* d_out, int out_size, void* d_ws, size_t ws_size,
                              hipStream_t stream) {
  const float* x = (const float*)d_in[0];        // [4,4096,512]
  const float* centers = (const float*)d_in[1];  // [4096,512]
  const float* W = (const float*)d_in[2];        // [512,1024]
  const float* b = (const float*)d_in[3];        // [1024]
  float* out = (float*)d_out;                    // [4,4096,1024] fp32

  // cand records ([16384][16][16] u32 = 16.8 MB) live in d_out; proj overwrites last.
  unsigned* cand = (unsigned*)d_out;

  // workspace (~22.3 MB)
  char* ws = (char*)d_ws;
  _Float16* xh = (_Float16*)(ws);                 // 16.78 MB
  _Float16* ch = (_Float16*)(ws + 16777216);      // 4.19 MB
  _Float16* whT = (_Float16*)(ws + 20971520);     // 1.05 MB
  float* c2 = (float*)(ws + 22020096);            // 16 KB
  unsigned* wthr = (unsigned*)(ws + 22036480);    // 64 KB
  u64* best = (u64*)(ws + 22102016);              // 128 KB

  cvt_all_kernel<<<Mc / 4 + Kc / 4 + 256, 256, 0, stream>>>(x, xh, wthr, centers,
                                                            ch, c2, W, whT);

  for (int half = 0; half < 2; ++half) {
    const int hb = half * NHALF;
    dist_hh_kernel<<<(Mc / 256) * (NHALF / 256), 512, 0, stream>>>(
        xh, ch + (size_t)hb * Dc, c2 + hb, wthr, cand, half * 8);
  }
  scan_refine_kernel<<<Mc / 4, 256, 0, stream>>>(cand, wthr, x, centers, best);
  proj_mfma_kernel<<<256, 512, 0, stream>>>(ch, best, whT, b, out);
}

// Round 7
// 246.903 us; speedup vs baseline: 1.9699x; 1.0011x over previous
//
#include <hip/hip_runtime.h>
#include <float.h>
#include <stdint.h>

#define EPSF 1e-6f

constexpr int Dc = 512, Kc = 4096, DOc = 1024;
constexpr int Mc = 16384;                 // 4*4096 rows

typedef _Float16 f16x8 __attribute__((ext_vector_type(8)));
typedef float f32x4 __attribute__((ext_vector_type(4)));
typedef __attribute__((address_space(1))) unsigned int gu32;
typedef __attribute__((address_space(3))) unsigned int lu32;
typedef unsigned long long u64;

// ---------- fused converts: x (f16 + window), centers (f16 + c2), W^T ----------
__global__ __launch_bounds__(256) void cvt_all_kernel(
    const float* __restrict__ x, _Float16* __restrict__ xh, unsigned* __restrict__ wthr,
    const float* __restrict__ centers, _Float16* __restrict__ ch, float* __restrict__ c2,
    const float* __restrict__ W, _Float16* __restrict__ whT) {
  const int bid = blockIdx.x;
  const int lane = threadIdx.x & 63, w = threadIdx.x >> 6;
  if (bid < Mc / 4) {
    const int row = bid * 4 + w;
    const size_t base = (size_t)row * Dc + lane * 8;
    float4 v0 = *(const float4*)(x + base);
    float4 v1 = *(const float4*)(x + base + 4);
    float v[8] = {v0.x, v0.y, v0.z, v0.w, v1.x, v1.y, v1.z, v1.w};
    f16x8 h;
    float s = 0.f;
#pragma unroll
    for (int i = 0; i < 8; ++i) {
      const float q = v[i] + EPSF;
      h[i] = (_Float16)q;
      s += q * q;
    }
    *(f16x8*)(xh + base) = h;
#pragma unroll
    for (int m = 1; m < 64; m <<= 1) s += __shfl_xor(s, m, 64);
    // window (u16 quant units): 64*[2(2e+e^2)*||c||max*||x||] + slack; e=2^-11
    if (lane == 0) wthr[row] = (unsigned)(2.829f * sqrtf(s) + 8.0f);
  } else if (bid < Mc / 4 + Kc / 4) {
    const int row = (bid - Mc / 4) * 4 + w;
    const size_t base = (size_t)row * Dc + lane * 8;
    float4 v0 = *(const float4*)(centers + base);
    float4 v1 = *(const float4*)(centers + base + 4);
    float v[8] = {v0.x, v0.y, v0.z, v0.w, v1.x, v1.y, v1.z, v1.w};
    f16x8 h;
    float s = 0.f;
#pragma unroll
    for (int i = 0; i < 8; ++i) { s += v[i] * v[i]; h[i] = (_Float16)v[i]; }
    *(f16x8*)(ch + base) = h;
#pragma unroll
    for (int off = 32; off > 0; off >>= 1) s += __shfl_down(s, off, 64);
    if (lane == 0) c2[row] = s;
  } else {
    const int g = (bid - Mc / 4 - Kc / 4) * 256 + threadIdx.x;
    const int n = g & (DOc - 1), d8 = g >> 10;
    f16x8 h;
#pragma unroll
    for (int r = 0; r < 8; ++r) h[r] = (_Float16)W[(size_t)(d8 * 8 + r) * DOc + n];
    *(f16x8*)(whT + (size_t)n * Dc + d8 * 8) = h;
  }
}

// ---------- distance GEMM: BM=128 BN=256 BK=32, 4 waves, 2 blocks/CU ----------
// Round-7 restructure: regs (~228/wave) cap us at 2 waves/SIMD; the old 512-thread
// 1-block/CU config had ONE barrier group -> every barrier stalled the whole CU.
// 256-thread blocks at 48KB LDS give 2 INDEPENDENT blocks/CU (forced by
// __launch_bounds__(256,2)): block B's waves fill block A's barrier bubbles.
// Swizzle for 64B rows: chunk ^= (row>>1)&3 (2-way bank aliasing = free).
// Counted gate vmcnt(6): stage()=6 loads, depth-2 prefetch, never 0 in loop.
// Both halves merged: one 2048-block launch. FP accumulation order unchanged.
__global__ __launch_bounds__(256, 2) void dist_hh_kernel(
    const _Float16* __restrict__ xh, const _Float16* __restrict__ chh,
    const float* __restrict__ c2h, const unsigned* __restrict__ wthr,
    unsigned* __restrict__ cand) {
  constexpr int BM = 128, BN = 256, BK = 32;
  constexpr int NT = Dc / BK;   // 16 K-tiles
  constexpr int SLOT = 12288;   // f16 per slot: A 128*32=4096 | B 256*32=8192
  __shared__ __align__(16) char smem_raw[49152];  // 2 slots = 48 KB
  _Float16* smem = (_Float16*)smem_raw;

  const int tid = threadIdx.x;  // 0..255
  const int lane = tid & 63;
  const int wid = tid >> 6;               // 0..3
  const int wm = wid >> 1, wn = wid & 1;  // 2(M) x 2(N) wave grid, wave tile 64x128
  const int fr = lane & 15, kq = lane >> 4;

  // XCD swizzle: bijective, each XCD gets contiguous swz chunk; within a chunk
  // one row-panel's 16 col-panels run back-to-back (A-panel hot in L2).
  const int fid = blockIdx.x;
  const int swz = (fid & 7) * 256 + (fid >> 3);
  const int rp = swz >> 4, cp = swz & 15;
  const int row0 = rp * BM;   // 128 row-panels
  const int n0 = cp * BN;     // 16 col-panels (global over both halves)

  // staging: 256 threads = 64 rows x 4 chunks (16B) per round
  const int sr = tid >> 2;                 // row within round
  const int sc = tid & 3;                  // dest chunk
  const int csrc = sc ^ ((sr >> 1) & 3);   // pre-swizzled source chunk
  const int sw = (fr >> 1) & 3;            // read-side swizzle constant

  f32x4 acc[4][8];
#pragma unroll
  for (int i = 0; i < 4; ++i)
#pragma unroll
    for (int j = 0; j < 8; ++j) acc[i][j] = (f32x4){0.f, 0.f, 0.f, 0.f};

  auto stage = [&](int kt) {  // 6 global_load_lds (A:2, B:4)
    const int p = kt & 1;
    const int d0 = kt * BK;
    _Float16* Ab = smem + p * SLOT;
    _Float16* Bb = Ab + 4096;
#pragma unroll
    for (int ld = 0; ld < 2; ++ld) {
      const int r = ld * 64 + sr;
      const size_t gA = (size_t)(row0 + r) * Dc + d0 + csrc * 8;
      __builtin_amdgcn_global_load_lds((const gu32*)(xh + gA),
                                       (lu32*)(Ab + r * 32 + sc * 8), 16, 0, 0);
    }
#pragma unroll
    for (int ld = 0; ld < 4; ++ld) {
      const int r = ld * 64 + sr;
      const size_t gB = (size_t)(n0 + r) * Dc + d0 + csrc * 8;
      __builtin_amdgcn_global_load_lds((const gu32*)(chh + gB),
                                       (lu32*)(Bb + r * 32 + sc * 8), 16, 0, 0);
    }
  };

  stage(0);
  stage(1);
  asm volatile("s_waitcnt vmcnt(6)" ::: "memory");  // tile 0 landed, tile 1 in flight
  __builtin_amdgcn_sched_barrier(0);
  __builtin_amdgcn_s_barrier();

  for (int kt = 0; kt < NT; ++kt) {
    const int p = kt & 1;
    const _Float16* Ab = smem + p * SLOT;
    const _Float16* Bb = Ab + 4096;
    const int co = (kq ^ sw) * 8;  // swizzled 16B chunk offset (f16 idx)
    f16x8 a[4], b[4];
#pragma unroll
    for (int nh = 0; nh < 2; ++nh) {  // sub-phase = 16-MFMA cluster
      if (nh == 0) {
#pragma unroll
        for (int m = 0; m < 4; ++m)
          a[m] = *(const f16x8*)&Ab[(wm * 64 + 16 * m + fr) * 32 + co];
      }
#pragma unroll
      for (int n = 0; n < 4; ++n)
        b[n] = *(const f16x8*)&Bb[(wn * 128 + nh * 64 + 16 * n + fr) * 32 + co];
      __builtin_amdgcn_s_barrier();
      asm volatile("s_waitcnt lgkmcnt(0)" ::: "memory");
      __builtin_amdgcn_s_setprio(1);
#pragma unroll
      for (int m = 0; m < 4; ++m)
#pragma unroll
        for (int n = 0; n < 4; ++n)
          acc[m][nh * 4 + n] =
              __builtin_amdgcn_mfma_f32_16x16x32_f16(a[m], b[n], acc[m][nh * 4 + n], 0, 0, 0);
      __builtin_amdgcn_s_setprio(0);
      __builtin_amdgcn_s_barrier();
    }
    if (kt + 2 < NT) {
      stage(kt + 2);  // slot p free: all reads of tile kt serviced pre-barrier
      asm volatile("s_waitcnt vmcnt(6)" ::: "memory");  // tile kt+1 landed
    } else {
      asm volatile("s_waitcnt vmcnt(0)" ::: "memory");  // drain final tile
    }
    __builtin_amdgcn_sched_barrier(0);
    __builtin_amdgcn_s_barrier();
  }

  // ---- compact epilogue (128 rows): per-row block-min + windowed candidates ----
  // Record per (row, 256-col block): 64B = {min<<16|cnt, 14 x (dq<<8|col), pad}.
  // Stored set = {dq <= localmin + wthr}: superset of global-window candidates.
  unsigned short* rmin = (unsigned short*)smem_raw;           // [128][2]
  unsigned short* bmin = (unsigned short*)(smem_raw + 512);   // [128]
  unsigned* rcnt = (unsigned*)(smem_raw + 1024);              // [128]
  unsigned* rthr = (unsigned*)(smem_raw + 1536);              // [128]
  unsigned* rcand = (unsigned*)(smem_raw + 2048);             // [128][14]

  if (tid < 128) {
    rcnt[tid] = 0u;
    rthr[tid] = wthr[row0 + tid];
  }

  float c2v[8];
#pragma unroll
  for (int j = 0; j < 8; ++j)
    c2v[j] = c2h[n0 + wn * 128 + (j >> 2) * 64 + 16 * (j & 3) + fr];

  auto quant = [](float d) -> unsigned {
    int u = __float2int_rn((d + 256.0f) * 32.0f);
    return (unsigned)min(65535, max(0, u));
  };

  // pass 1: per-lane row mins over this lane's 8 cols, then fr-group reduce
  unsigned pm[16];
#pragma unroll
  for (int i = 0; i < 4; ++i)
#pragma unroll
    for (int reg = 0; reg < 4; ++reg) {
      unsigned mn = 0xFFFFu;
#pragma unroll
      for (int j = 0; j < 8; ++j)
        mn = min(mn, quant(c2v[j] - 2.0f * acc[i][j][reg]));
      pm[i * 4 + reg] = mn;
    }
#pragma unroll
  for (int d = 1; d < 16; d <<= 1)
#pragma unroll
    for (int k = 0; k < 16; ++k)
      pm[k] = min(pm[k], (unsigned)__shfl_xor((int)pm[k], d, 64));
  if (fr == 0) {
#pragma unroll
    for (int k = 0; k < 16; ++k)
      rmin[(wm * 64 + 16 * (k >> 2) + 4 * kq + (k & 3)) * 2 + wn] = (unsigned short)pm[k];
  }
  __syncthreads();
  if (tid < 128) bmin[tid] = min(rmin[2 * tid], rmin[2 * tid + 1]);
  __syncthreads();

  // pass 2: windowed append (superset of global candidates)
#pragma unroll
  for (int i = 0; i < 4; ++i)
#pragma unroll
    for (int reg = 0; reg < 4; ++reg) {
      const int row = wm * 64 + 16 * i + 4 * kq + reg;
      const unsigned lim = (unsigned)bmin[row] + rthr[row];
#pragma unroll
      for (int j = 0; j < 8; ++j) {
        const unsigned dqv = quant(c2v[j] - 2.0f * acc[i][j][reg]);
        if (dqv <= lim) {
          const unsigned slot = atomicAdd(&rcnt[row], 1u);
          if (slot < 14u)
            rcand[row * 14 + slot] =
                (dqv << 8) | (unsigned)(wn * 128 + (j >> 2) * 64 + 16 * (j & 3) + fr);
        }
      }
    }
  __syncthreads();

  // write 64B record per row: {min<<16|cnt, c0..c13, 0}
#pragma unroll
  for (int rr = 0; rr < 2; ++rr) {
    const int row = rr * 64 + (tid >> 2), part = tid & 3;
    unsigned cnt = rcnt[row];
    if (cnt > 65535u) cnt = 65535u;
    unsigned vals[4];
#pragma unroll
    for (int q = 0; q < 4; ++q) {
      const int wd = part * 4 + q;
      unsigned v;
      if (wd == 0) v = ((unsigned)bmin[row] << 16) | cnt;
      else if (wd <= 14) v = rcand[row * 14 + wd - 1];
      else v = 0u;
      vals[q] = v;
    }
    *(uint4*)(cand + ((size_t)(row0 + row) * 16 + cp) * 16 + part * 4) =
        (uint4){vals[0], vals[1], vals[2], vals[3]};
  }
}

// ---------- scan records + fp64 refine: one wave per row, single pass ----------
__global__ __launch_bounds__(256) void scan_refine_kernel(
    const unsigned* __restrict__ cand, const unsigned* __restrict__ wthr,
    const float* __restrict__ x, const float* __restrict__ centers,
    u64* __restrict__ best) {
  const int w = threadIdx.x >> 6, l = threadIdx.x & 63;
  const int row = blockIdx.x * 4 + w;
  // 16 records x 16 u32 per row; lane l owns record l>>2, words (l&3)*4..+3
  const uint4 rv = *(const uint4*)(cand + (size_t)row * 256 + l * 4);
  const int w0 = (l & 3) * 4;

  // global quantized min over 16 block mins
  unsigned mn = 0xFFFFu;
  if (w0 == 0) mn = rv.x >> 16;
#pragma unroll
  for (int m = 1; m < 64; m <<= 1) mn = min(mn, (unsigned)__shfl_xor((int)mn, m, 64));
  const unsigned thr = mn + wthr[row];

  // record's cnt broadcast to its 4 lanes
  const unsigned cnt = ((unsigned)__shfl((int)rv.x, l & ~3)) & 0xFFFFu;

  // preload x row (fp32), 8 elems/lane
  const float* xr = x + (size_t)row * Dc + l * 8;
  float4 a0 = *(const float4*)xr, a1 = *(const float4*)(xr + 4);
  const float xa[8] = {a0.x, a0.y, a0.z, a0.w, a1.x, a1.y, a1.z, a1.w};
  double xq[8];
#pragma unroll
  for (int i = 0; i < 8; ++i) xq[i] = (double)(xa[i] + EPSF);  // fp32 x+eps, as reference

  u64 bk = ~0ULL;
  auto refine = [&](int g) {
    const float* cr = centers + (size_t)g * Dc + l * 8;
    float4 b0 = *(const float4*)cr, b1 = *(const float4*)(cr + 4);
    const float ca[8] = {b0.x, b0.y, b0.z, b0.w, b1.x, b1.y, b1.z, b1.w};
    double s = 0.0;
#pragma unroll
    for (int i = 0; i < 8; ++i) {
      const double cd = (double)ca[i];
      s += cd * cd - 2.0 * xq[i] * cd;
    }
#pragma unroll
    for (int mm = 1; mm < 64; mm <<= 1) s += __shfl_xor(s, mm, 64);
    const u64 key =
        ((u64)__double_as_longlong(s + 16384.0) & ~0xFFFULL) | (unsigned)g;
    bk = min(bk, key);
  };

  const unsigned wv[4] = {rv.x, rv.y, rv.z, rv.w};
#pragma unroll
  for (int i = 0; i < 4; ++i) {
    const int wi = w0 + i;  // word index within record
    const bool valid = (wi >= 1) && (wi <= 14) && ((unsigned)(wi - 1) < cnt) &&
                       (cnt <= 14u) && ((wv[i] >> 8) <= thr);
    u64 m = __ballot(valid);
    while (m) {
      const int ln = __ffsll((long long)m) - 1;
      m &= m - 1;
      const unsigned cw = (unsigned)__shfl((int)wv[i], ln);
      refine((ln >> 2) * 256 + (int)(cw & 0xFFu));
    }
  }
  // overflow records (cnt>14): refine whole 256-block (correctness net; ~never)
  {
    u64 md = __ballot((w0 == 0) && (cnt > 14u));
    while (md) {
      const int ln = __ffsll((long long)md) - 1;
      md &= md - 1;
      const int blk = ln >> 2;
      for (int c = 0; c < 256; ++c) refine(blk * 256 + c);
    }
  }
  if (l == 0) best[row] = bk;
}

// ---------- projection: out = centers[best] @ W + b  (256x256, dist-r6 skeleton) ----------
__global__ __launch_bounds__(512, 2) void proj_mfma_kernel(
    const _Float16* __restrict__ ch, const u64* __restrict__ best,
    const _Float16* __restrict__ whT, const float* __restrict__ bias,
    float* __restrict__ out) {
  constexpr int BM = 256, BN = 256, BK = 64;
  constexpr int NT = Dc / BK;  // 8 K-tiles
  __shared__ __align__(16) _Float16 smem[4 * 16384];  // 128 KB: 2 slots x (A|B)
  __shared__ int ssel[BM];

  const int tid = threadIdx.x;  // 0..511
  const int lane = tid & 63;
  const int wid = tid >> 6;
  const int wm = wid >> 1, wn = wid & 1;  // 4(M) x 2(N)
  const int fr = lane & 15, kq = lane >> 4;
  const int row0 = (blockIdx.x >> 2) * BM;  // 64 row-panels
  const int n0 = (blockIdx.x & 3) * BN;     // 4 col-panels (DOc=1024)

  const int sr = tid >> 3;
  const int sc = tid & 7;
  const int csrc = sc ^ (sr & 7);
  const int sw = fr & 7;

  if (tid < 256) ssel[tid] = (int)(best[row0 + tid] & 0xFFFULL);
  __syncthreads();

  f32x4 acc[4][8];
#pragma unroll
  for (int i = 0; i < 4; ++i)
#pragma unroll
    for (int j = 0; j < 8; ++j) acc[i][j] = (f32x4){0.f, 0.f, 0.f, 0.f};

  auto stage = [&](int kt) {
    const int p = kt & 1;
    const int d0 = kt * BK;
    _Float16* Ab = smem + p * 16384;
    _Float16* Bb = smem + 32768 + p * 16384;
#pragma unroll
    for (int ld = 0; ld < 4; ++ld) {
      const int r = ld * 64 + sr;
      const size_t gA = (size_t)ssel[r] * Dc + d0 + csrc * 8;
      const size_t gB = (size_t)(n0 + r) * Dc + d0 + csrc * 8;
      const int lo = r * 64 + sc * 8;
      __builtin_amdgcn_global_load_lds((const gu32*)(ch + gA), (lu32*)(Ab + lo), 16, 0, 0);
      __builtin_amdgcn_global_load_lds((const gu32*)(whT + gB), (lu32*)(Bb + lo), 16, 0, 0);
    }
  };

  stage(0);
  stage(1);
  asm volatile("s_waitcnt vmcnt(8)" ::: "memory");
  __builtin_amdgcn_sched_barrier(0);
  __builtin_amdgcn_s_barrier();

  for (int kt = 0; kt < NT; ++kt) {
    const int p = kt & 1;
    const _Float16* Ab = smem + p * 16384;
    const _Float16* Bb = smem + 32768 + p * 16384;
    f16x8 a[4], b[4];
#pragma unroll
    for (int s = 0; s < 4; ++s) {
      const int kh = s >> 1, nh = s & 1;
      const int co = ((kh * 4 + kq) ^ sw) * 8;
      if (nh == 0) {
#pragma unroll
        for (int m = 0; m < 4; ++m)
          a[m] = *(const f16x8*)&Ab[(wm * 64 + 16 * m + fr) * 64 + co];
      }
#pragma unroll
      for (int n = 0; n < 4; ++n)
        b[n] = *(const f16x8*)&Bb[(wn * 128 + nh * 64 + 16 * n + fr) * 64 + co];
      __builtin_amdgcn_s_barrier();
      asm volatile("s_waitcnt lgkmcnt(0)" ::: "memory");
      __builtin_amdgcn_s_setprio(1);
#pragma unroll
      for (int m = 0; m < 4; ++m)
#pragma unroll
        for (int n = 0; n < 4; ++n)
          acc[m][nh * 4 + n] =
              __builtin_amdgcn_mfma_f32_16x16x32_f16(a[m], b[n], acc[m][nh * 4 + n], 0, 0, 0);
      __builtin_amdgcn_s_setprio(0);
      __builtin_amdgcn_s_barrier();
    }
    if (kt + 2 < NT) {
      stage(kt + 2);
      asm volatile("s_waitcnt vmcnt(8)" ::: "memory");
    } else {
      asm volatile("s_waitcnt vmcnt(0)" ::: "memory");
    }
    __builtin_amdgcn_sched_barrier(0);
    __builtin_amdgcn_s_barrier();
  }

  // epilogue: direct f32 stores + bias
#pragma unroll
  for (int j = 0; j < 8; ++j) {
    const int col = n0 + wn * 128 + (j >> 2) * 64 + 16 * (j & 3) + fr;
    const float bb = bias[col];
#pragma unroll
    for (int i = 0; i < 4; ++i)
#pragma unroll
      for (int reg = 0; reg < 4; ++reg)
        out[(size_t)(row0 + wm * 64 + 16 * i + 4 * kq + reg) * DOc + col] =
            acc[i][j][reg] + bb;
  }
}

extern "C" void kernel_launch(void* const* d_in, const int* in_sizes, int n_in,
                              void* d_out, int out_size, void* d_ws, size_t ws_size,
                              hipStream_t stream) {
  const float* x = (const float*)d_in[0];        // [4,4096,512]
  const float* centers = (const float*)d_in[1];  // [4096,512]
  const float* W = (const float*)d_in[2];        // [512,1024]
  const float* b = (const float*)d_in[3];        // [1024]
  float* out = (float*)d_out;                    // [4,4096,1024] fp32

  // cand records ([16384][16][16] u32 = 16.8 MB) live in d_out; proj overwrites last.
  unsigned* cand = (unsigned*)d_out;

  // workspace (~22.3 MB)
  char* ws = (char*)d_ws;
  _Float16* xh = (_Float16*)(ws);                 // 16.78 MB
  _Float16* ch = (_Float16*)(ws + 16777216);      // 4.19 MB
  _Float16* whT = (_Float16*)(ws + 20971520);     // 1.05 MB
  float* c2 = (float*)(ws + 22020096);            // 16 KB
  unsigned* wthr = (unsigned*)(ws + 22036480);    // 64 KB
  u64* best = (u64*)(ws + 22102016);              // 128 KB

  cvt_all_kernel<<<Mc / 4 + Kc / 4 + 256, 256, 0, stream>>>(x, xh, wthr, centers,
                                                            ch, c2, W, whT);
  dist_hh_kernel<<<(Mc / 128) * (Kc / 256), 256, 0, stream>>>(xh, ch, c2, wthr, cand);
  scan_refine_kernel<<<Mc / 4, 256, 0, stream>>>(cand, wthr, x, centers, best);
  proj_mfma_kernel<<<256, 512, 0, stream>>>(ch, best, whT, b, out);
}

// Round 8
// 246.725 us; speedup vs baseline: 1.9713x; 1.0007x over previous
//
#include <hip/hip_runtime.h>
#include <float.h>
#include <stdint.h>

#define EPSF 1e-6f

constexpr int Dc = 512, Kc = 4096, DOc = 1024;
constexpr int Mc = 16384;                 // 4*4096 rows

typedef _Float16 f16x8 __attribute__((ext_vector_type(8)));
typedef float f32x4 __attribute__((ext_vector_type(4)));
typedef __attribute__((address_space(1))) unsigned int gu32;
typedef __attribute__((address_space(3))) unsigned int lu32;
typedef unsigned long long u64;

// ---------- fused converts: x (f16 + window), centers (f16 + c2), W^T ----------
__global__ __launch_bounds__(256) void cvt_all_kernel(
    const float* __restrict__ x, _Float16* __restrict__ xh, unsigned* __restrict__ wthr,
    const float* __restrict__ centers, _Float16* __restrict__ ch, float* __restrict__ c2,
    const float* __restrict__ W, _Float16* __restrict__ whT) {
  const int bid = blockIdx.x;
  const int lane = threadIdx.x & 63, w = threadIdx.x >> 6;
  if (bid < Mc / 4) {
    const int row = bid * 4 + w;
    const size_t base = (size_t)row * Dc + lane * 8;
    float4 v0 = *(const float4*)(x + base);
    float4 v1 = *(const float4*)(x + base + 4);
    float v[8] = {v0.x, v0.y, v0.z, v0.w, v1.x, v1.y, v1.z, v1.w};
    f16x8 h;
    float s = 0.f;
#pragma unroll
    for (int i = 0; i < 8; ++i) {
      const float q = v[i] + EPSF;
      h[i] = (_Float16)q;
      s += q * q;
    }
    *(f16x8*)(xh + base) = h;
#pragma unroll
    for (int m = 1; m < 64; m <<= 1) s += __shfl_xor(s, m, 64);
    // window (u16 quant units): 64*[2(2e+e^2)*||c||max*||x||] + slack; e=2^-11
    if (lane == 0) wthr[row] = (unsigned)(2.829f * sqrtf(s) + 8.0f);
  } else if (bid < Mc / 4 + Kc / 4) {
    const int row = (bid - Mc / 4) * 4 + w;
    const size_t base = (size_t)row * Dc + lane * 8;
    float4 v0 = *(const float4*)(centers + base);
    float4 v1 = *(const float4*)(centers + base + 4);
    float v[8] = {v0.x, v0.y, v0.z, v0.w, v1.x, v1.y, v1.z, v1.w};
    f16x8 h;
    float s = 0.f;
#pragma unroll
    for (int i = 0; i < 8; ++i) { s += v[i] * v[i]; h[i] = (_Float16)v[i]; }
    *(f16x8*)(ch + base) = h;
#pragma unroll
    for (int off = 32; off > 0; off >>= 1) s += __shfl_down(s, off, 64);
    if (lane == 0) c2[row] = s;
  } else {
    const int g = (bid - Mc / 4 - Kc / 4) * 256 + threadIdx.x;
    const int n = g & (DOc - 1), d8 = g >> 10;
    f16x8 h;
#pragma unroll
    for (int r = 0; r < 8; ++r) h[r] = (_Float16)W[(size_t)(d8 * 8 + r) * DOc + n];
    *(f16x8*)(whT + (size_t)n * Dc + d8 * 8) = h;
  }
}

// ---------- distance GEMM: BM=128 BN=256 BK=32, 4 waves, 2 blocks/CU ----------
// (byte-identical to round-7 passing build)
__global__ __launch_bounds__(256, 2) void dist_hh_kernel(
    const _Float16* __restrict__ xh, const _Float16* __restrict__ chh,
    const float* __restrict__ c2h, const unsigned* __restrict__ wthr,
    unsigned* __restrict__ cand) {
  constexpr int BM = 128, BN = 256, BK = 32;
  constexpr int NT = Dc / BK;   // 16 K-tiles
  constexpr int SLOT = 12288;   // f16 per slot: A 128*32=4096 | B 256*32=8192
  __shared__ __align__(16) char smem_raw[49152];  // 2 slots = 48 KB
  _Float16* smem = (_Float16*)smem_raw;

  const int tid = threadIdx.x;  // 0..255
  const int lane = tid & 63;
  const int wid = tid >> 6;               // 0..3
  const int wm = wid >> 1, wn = wid & 1;  // 2(M) x 2(N) wave grid, wave tile 64x128
  const int fr = lane & 15, kq = lane >> 4;

  const int fid = blockIdx.x;
  const int swz = (fid & 7) * 256 + (fid >> 3);
  const int rp = swz >> 4, cp = swz & 15;
  const int row0 = rp * BM;   // 128 row-panels
  const int n0 = cp * BN;     // 16 col-panels

  const int sr = tid >> 2;                 // row within round
  const int sc = tid & 3;                  // dest chunk
  const int csrc = sc ^ ((sr >> 1) & 3);   // pre-swizzled source chunk
  const int sw = (fr >> 1) & 3;            // read-side swizzle constant

  f32x4 acc[4][8];
#pragma unroll
  for (int i = 0; i < 4; ++i)
#pragma unroll
    for (int j = 0; j < 8; ++j) acc[i][j] = (f32x4){0.f, 0.f, 0.f, 0.f};

  auto stage = [&](int kt) {  // 6 global_load_lds (A:2, B:4)
    const int p = kt & 1;
    const int d0 = kt * BK;
    _Float16* Ab = smem + p * SLOT;
    _Float16* Bb = Ab + 4096;
#pragma unroll
    for (int ld = 0; ld < 2; ++ld) {
      const int r = ld * 64 + sr;
      const size_t gA = (size_t)(row0 + r) * Dc + d0 + csrc * 8;
      __builtin_amdgcn_global_load_lds((const gu32*)(xh + gA),
                                       (lu32*)(Ab + r * 32 + sc * 8), 16, 0, 0);
    }
#pragma unroll
    for (int ld = 0; ld < 4; ++ld) {
      const int r = ld * 64 + sr;
      const size_t gB = (size_t)(n0 + r) * Dc + d0 + csrc * 8;
      __builtin_amdgcn_global_load_lds((const gu32*)(chh + gB),
                                       (lu32*)(Bb + r * 32 + sc * 8), 16, 0, 0);
    }
  };

  stage(0);
  stage(1);
  asm volatile("s_waitcnt vmcnt(6)" ::: "memory");
  __builtin_amdgcn_sched_barrier(0);
  __builtin_amdgcn_s_barrier();

  for (int kt = 0; kt < NT; ++kt) {
    const int p = kt & 1;
    const _Float16* Ab = smem + p * SLOT;
    const _Float16* Bb = Ab + 4096;
    const int co = (kq ^ sw) * 8;  // swizzled 16B chunk offset (f16 idx)
    f16x8 a[4], b[4];
#pragma unroll
    for (int nh = 0; nh < 2; ++nh) {  // sub-phase = 16-MFMA cluster
      if (nh == 0) {
#pragma unroll
        for (int m = 0; m < 4; ++m)
          a[m] = *(const f16x8*)&Ab[(wm * 64 + 16 * m + fr) * 32 + co];
      }
#pragma unroll
      for (int n = 0; n < 4; ++n)
        b[n] = *(const f16x8*)&Bb[(wn * 128 + nh * 64 + 16 * n + fr) * 32 + co];
      __builtin_amdgcn_s_barrier();
      asm volatile("s_waitcnt lgkmcnt(0)" ::: "memory");
      __builtin_amdgcn_s_setprio(1);
#pragma unroll
      for (int m = 0; m < 4; ++m)
#pragma unroll
        for (int n = 0; n < 4; ++n)
          acc[m][nh * 4 + n] =
              __builtin_amdgcn_mfma_f32_16x16x32_f16(a[m], b[n], acc[m][nh * 4 + n], 0, 0, 0);
      __builtin_amdgcn_s_setprio(0);
      __builtin_amdgcn_s_barrier();
    }
    if (kt + 2 < NT) {
      stage(kt + 2);
      asm volatile("s_waitcnt vmcnt(6)" ::: "memory");
    } else {
      asm volatile("s_waitcnt vmcnt(0)" ::: "memory");
    }
    __builtin_amdgcn_sched_barrier(0);
    __builtin_amdgcn_s_barrier();
  }

  // ---- compact epilogue (128 rows): per-row block-min + windowed candidates ----
  unsigned short* rmin = (unsigned short*)smem_raw;           // [128][2]
  unsigned short* bmin = (unsigned short*)(smem_raw + 512);   // [128]
  unsigned* rcnt = (unsigned*)(smem_raw + 1024);              // [128]
  unsigned* rthr = (unsigned*)(smem_raw + 1536);              // [128]
  unsigned* rcand = (unsigned*)(smem_raw + 2048);             // [128][14]

  if (tid < 128) {
    rcnt[tid] = 0u;
    rthr[tid] = wthr[row0 + tid];
  }

  float c2v[8];
#pragma unroll
  for (int j = 0; j < 8; ++j)
    c2v[j] = c2h[n0 + wn * 128 + (j >> 2) * 64 + 16 * (j & 3) + fr];

  auto quant = [](float d) -> unsigned {
    int u = __float2int_rn((d + 256.0f) * 32.0f);
    return (unsigned)min(65535, max(0, u));
  };

  unsigned pm[16];
#pragma unroll
  for (int i = 0; i < 4; ++i)
#pragma unroll
    for (int reg = 0; reg < 4; ++reg) {
      unsigned mn = 0xFFFFu;
#pragma unroll
      for (int j = 0; j < 8; ++j)
        mn = min(mn, quant(c2v[j] - 2.0f * acc[i][j][reg]));
      pm[i * 4 + reg] = mn;
    }
#pragma unroll
  for (int d = 1; d < 16; d <<= 1)
#pragma unroll
    for (int k = 0; k < 16; ++k)
      pm[k] = min(pm[k], (unsigned)__shfl_xor((int)pm[k], d, 64));
  if (fr == 0) {
#pragma unroll
    for (int k = 0; k < 16; ++k)
      rmin[(wm * 64 + 16 * (k >> 2) + 4 * kq + (k & 3)) * 2 + wn] = (unsigned short)pm[k];
  }
  __syncthreads();
  if (tid < 128) bmin[tid] = min(rmin[2 * tid], rmin[2 * tid + 1]);
  __syncthreads();

#pragma unroll
  for (int i = 0; i < 4; ++i)
#pragma unroll
    for (int reg = 0; reg < 4; ++reg) {
      const int row = wm * 64 + 16 * i + 4 * kq + reg;
      const unsigned lim = (unsigned)bmin[row] + rthr[row];
#pragma unroll
      for (int j = 0; j < 8; ++j) {
        const unsigned dqv = quant(c2v[j] - 2.0f * acc[i][j][reg]);
        if (dqv <= lim) {
          const unsigned slot = atomicAdd(&rcnt[row], 1u);
          if (slot < 14u)
            rcand[row * 14 + slot] =
                (dqv << 8) | (unsigned)(wn * 128 + (j >> 2) * 64 + 16 * (j & 3) + fr);
        }
      }
    }
  __syncthreads();

#pragma unroll
  for (int rr = 0; rr < 2; ++rr) {
    const int row = rr * 64 + (tid >> 2), part = tid & 3;
    unsigned cnt = rcnt[row];
    if (cnt > 65535u) cnt = 65535u;
    unsigned vals[4];
#pragma unroll
    for (int q = 0; q < 4; ++q) {
      const int wd = part * 4 + q;
      unsigned v;
      if (wd == 0) v = ((unsigned)bmin[row] << 16) | cnt;
      else if (wd <= 14) v = rcand[row * 14 + wd - 1];
      else v = 0u;
      vals[q] = v;
    }
    *(uint4*)(cand + ((size_t)(row0 + row) * 16 + cp) * 16 + part * 4) =
        (uint4){vals[0], vals[1], vals[2], vals[3]};
  }
}

// ---------- scan records + fp64 refine: one wave per row, single pass ----------
__global__ __launch_bounds__(256) void scan_refine_kernel(
    const unsigned* __restrict__ cand, const unsigned* __restrict__ wthr,
    const float* __restrict__ x, const float* __restrict__ centers,
    u64* __restrict__ best) {
  const int w = threadIdx.x >> 6, l = threadIdx.x & 63;
  const int row = blockIdx.x * 4 + w;
  const uint4 rv = *(const uint4*)(cand + (size_t)row * 256 + l * 4);
  const int w0 = (l & 3) * 4;

  unsigned mn = 0xFFFFu;
  if (w0 == 0) mn = rv.x >> 16;
#pragma unroll
  for (int m = 1; m < 64; m <<= 1) mn = min(mn, (unsigned)__shfl_xor((int)mn, m, 64));
  const unsigned thr = mn + wthr[row];

  const unsigned cnt = ((unsigned)__shfl((int)rv.x, l & ~3)) & 0xFFFFu;

  const float* xr = x + (size_t)row * Dc + l * 8;
  float4 a0 = *(const float4*)xr, a1 = *(const float4*)(xr + 4);
  const float xa[8] = {a0.x, a0.y, a0.z, a0.w, a1.x, a1.y, a1.z, a1.w};
  double xq[8];
#pragma unroll
  for (int i = 0; i < 8; ++i) xq[i] = (double)(xa[i] + EPSF);

  u64 bk = ~0ULL;
  auto refine = [&](int g) {
    const float* cr = centers + (size_t)g * Dc + l * 8;
    float4 b0 = *(const float4*)cr, b1 = *(const float4*)(cr + 4);
    const float ca[8] = {b0.x, b0.y, b0.z, b0.w, b1.x, b1.y, b1.z, b1.w};
    double s = 0.0;
#pragma unroll
    for (int i = 0; i < 8; ++i) {
      const double cd = (double)ca[i];
      s += cd * cd - 2.0 * xq[i] * cd;
    }
#pragma unroll
    for (int mm = 1; mm < 64; mm <<= 1) s += __shfl_xor(s, mm, 64);
    const u64 key =
        ((u64)__double_as_longlong(s + 16384.0) & ~0xFFFULL) | (unsigned)g;
    bk = min(bk, key);
  };

  const unsigned wv[4] = {rv.x, rv.y, rv.z, rv.w};
#pragma unroll
  for (int i = 0; i < 4; ++i) {
    const int wi = w0 + i;
    const bool valid = (wi >= 1) && (wi <= 14) && ((unsigned)(wi - 1) < cnt) &&
                       (cnt <= 14u) && ((wv[i] >> 8) <= thr);
    u64 m = __ballot(valid);
    while (m) {
      const int ln = __ffsll((long long)m) - 1;
      m &= m - 1;
      const unsigned cw = (unsigned)__shfl((int)wv[i], ln);
      refine((ln >> 2) * 256 + (int)(cw & 0xFFu));
    }
  }
  {
    u64 md = __ballot((w0 == 0) && (cnt > 14u));
    while (md) {
      const int ln = __ffsll((long long)md) - 1;
      md &= md - 1;
      const int blk = ln >> 2;
      for (int c = 0; c < 256; ++c) refine(blk * 256 + c);
    }
  }
  if (l == 0) best[row] = bk;
}

// ---------- CW = centers @ W + b  (dense 128x128 f16 MFMA; r1-proj lineage) ----------
__global__ __launch_bounds__(256, 2) void cw_kernel(
    const _Float16* __restrict__ ch, const _Float16* __restrict__ whT,
    const float* __restrict__ bias, float* __restrict__ CW) {
  constexpr int BM = 128, BN = 128, BK = 32;
  constexpr int BUF = BM * BK + BN * BK;            // 8192 f16 per buffer
  __shared__ __align__(16) _Float16 smem[2 * BUF];  // 32 KB

  const int tid = threadIdx.x;
  const int lane = tid & 63, w = tid >> 6;
  const int row0 = blockIdx.x * BM;   // 32 row-panels (Kc=4096)
  const int n0 = blockIdx.y * BN;     // 8 col-panels (DOc=1024)
  const int srow = w * 16 + (lane >> 2);
  const int scol = (lane & 3) * 8;
  const int fr = lane & 15, kq = lane >> 4;
  const int m0 = w * 32;

  f32x4 acc[2][8];
#pragma unroll
  for (int i = 0; i < 2; ++i)
#pragma unroll
    for (int j = 0; j < 8; ++j) acc[i][j] = (f32x4){0.f, 0.f, 0.f, 0.f};

  auto stage = [&](int buf, int d0) {
    _Float16* sA_ = smem + buf * BUF;
    _Float16* sB_ = sA_ + BM * BK;
#pragma unroll
    for (int r = 0; r < 2; ++r) {
      const int rr = r * 64 + srow;
      const size_t gA = (size_t)(row0 + rr) * Dc + d0 + scol;
      const size_t gB = (size_t)(n0 + rr) * Dc + d0 + scol;
      const int lo = rr * BK + scol;
      __builtin_amdgcn_global_load_lds((const gu32*)(ch + gA), (lu32*)(sA_ + lo), 16, 0, 0);
      __builtin_amdgcn_global_load_lds((const gu32*)(whT + gB), (lu32*)(sB_ + lo), 16, 0, 0);
    }
  };

  constexpr int NSTEP = Dc / BK;  // 16
  stage(0, 0);
  __syncthreads();
  int cur = 0;
  for (int step = 0; step < NSTEP; ++step) {
    if (step + 1 < NSTEP) stage(cur ^ 1, (step + 1) * BK);

    const _Float16* sA = smem + cur * BUF;
    const _Float16* sB = sA + BM * BK;
    f16x8 a[2], b[8];
#pragma unroll
    for (int i = 0; i < 2; ++i)
      a[i] = *(const f16x8*)&sA[(m0 + 16 * i + fr) * BK + kq * 8];
#pragma unroll
    for (int j = 0; j < 8; ++j)
      b[j] = *(const f16x8*)&sB[(16 * j + fr) * BK + kq * 8];
#pragma unroll
    for (int i = 0; i < 2; ++i)
#pragma unroll
      for (int j = 0; j < 8; ++j)
        acc[i][j] = __builtin_amdgcn_mfma_f32_16x16x32_f16(a[i], b[j], acc[i][j], 0, 0, 0);

    __syncthreads();
    cur ^= 1;
  }

#pragma unroll
  for (int j = 0; j < 8; ++j) {
    const int col = n0 + 16 * j + fr;
    const float bb = bias[col];
#pragma unroll
    for (int i = 0; i < 2; ++i)
#pragma unroll
      for (int reg = 0; reg < 4; ++reg)
        CW[(size_t)(row0 + m0 + 16 * i + 4 * kq + reg) * DOc + col] =
            acc[i][j][reg] + bb;
  }
}

// ---------- proj = row gather: out[row] = CW[best[row] & 0xFFF] ----------
__global__ __launch_bounds__(256) void gather_kernel(
    const float* __restrict__ CW, const u64* __restrict__ best,
    float* __restrict__ out) {
  const int w = threadIdx.x >> 6, l = threadIdx.x & 63;
  const int row = blockIdx.x * 4 + w;
  const int sel = (int)(best[row] & 0xFFFULL);
  const float4* src = (const float4*)(CW + (size_t)sel * DOc);
  float4* dst = (float4*)(out + (size_t)row * DOc);
#pragma unroll
  for (int i = 0; i < 4; ++i) dst[l + 64 * i] = src[l + 64 * i];
}

extern "C" void kernel_launch(void* const* d_in, const int* in_sizes, int n_in,
                              void* d_out, int out_size, void* d_ws, size_t ws_size,
                              hipStream_t stream) {
  const float* x = (const float*)d_in[0];        // [4,4096,512]
  const float* centers = (const float*)d_in[1];  // [4096,512]
  const float* W = (const float*)d_in[2];        // [512,1024]
  const float* b = (const float*)d_in[3];        // [1024]
  float* out = (float*)d_out;                    // [4,4096,1024] fp32

  // cand records ([16384][16][16] u32 = 16.8 MB) live in d_out; gather overwrites last.
  unsigned* cand = (unsigned*)d_out;

  // workspace (~22.3 MB). CW (4096x1024 f32 = 16,777,216 B) ALIASES xh exactly:
  // xh is dead after dist, CW is produced after dist.
  char* ws = (char*)d_ws;
  _Float16* xh = (_Float16*)(ws);                 // 16.78 MB (phase 1)
  float* CW = (float*)(ws);                       // 16.78 MB (phase 2, aliases xh)
  _Float16* ch = (_Float16*)(ws + 16777216);      // 4.19 MB
  _Float16* whT = (_Float16*)(ws + 20971520);     // 1.05 MB
  float* c2 = (float*)(ws + 22020096);            // 16 KB
  unsigned* wthr = (unsigned*)(ws + 22036480);    // 64 KB
  u64* best = (u64*)(ws + 22102016);              // 128 KB

  cvt_all_kernel<<<Mc / 4 + Kc / 4 + 256, 256, 0, stream>>>(x, xh, wthr, centers,
                                                            ch, c2, W, whT);
  dist_hh_kernel<<<(Mc / 128) * (Kc / 256), 256, 0, stream>>>(xh, ch, c2, wthr, cand);
  scan_refine_kernel<<<Mc / 4, 256, 0, stream>>>(cand, wthr, x, centers, best);
  cw_kernel<<<dim3(Kc / 128, DOc / 128), 256, 0, stream>>>(ch, whT, b, CW);
  gather_kernel<<<Mc / 4, 256, 0, stream>>>(CW, best, out);
}